// Round 1
// baseline (227.286 us; speedup 1.0000x reference)
//
#include <hip/hip_runtime.h>

#define NSW 2
#define NDCT 32
#define NF 64
#define KDIM 2048          // 32 t * 64 spatial
#define SLOPE 0.02f
#define PI_F 3.14159265358979323846f

// ---------------------------------------------------------------------------
// Kernel 1: VeffT[s,k,o] = 0.125 * sum_{f,p,q} Ct[f,t] Cs[p,i] Cs[q,j] W[s,o,f,p,q]
// (k = t*64 + i*8 + j).  Transposed output so the GEMM reads weights
// wave-uniformly. 128 blocks, ~4-6 us (scattered 1 MiB store, L2-absorbed).
// ---------------------------------------------------------------------------
__global__ __launch_bounds__(256) void veff_kernel(const float* __restrict__ W,
                                                   float* __restrict__ VeffT) {
    __shared__ float Ct[32][32];   // [f][t] = 2*cos(pi*(2t+1)*f/64)
    __shared__ float Cs[8][8];     // [p][i] = 2*cos(pi*(2i+1)*p/16)
    __shared__ float bufA[2048];
    __shared__ float bufB[2048];
    const int tid = threadIdx.x;

    for (int idx = tid; idx < 1024; idx += 256) {
        int f = idx >> 5, t = idx & 31;
        Ct[f][t] = 2.0f * cosf(PI_F * (float)((2 * t + 1) * f) * (1.0f / 64.0f));
    }
    if (tid < 64) {
        int p = tid >> 3, i = tid & 7;
        Cs[p][i] = 2.0f * cosf(PI_F * (float)((2 * i + 1) * p) * (1.0f / 16.0f));
    }
    const float* Wso = W + blockIdx.x * 2048;   // [f(32)][p(8)][q(8)]
    for (int idx = tid; idx < 2048; idx += 256) bufA[idx] = Wso[idx];
    __syncthreads();

    for (int idx = tid; idx < 2048; idx += 256) {       // contract f
        int t = idx >> 6, pq = idx & 63;
        float acc = 0.f;
        #pragma unroll
        for (int f = 0; f < 32; ++f) acc += Ct[f][t] * bufA[f * 64 + pq];
        bufB[idx] = acc;
    }
    __syncthreads();
    for (int idx = tid; idx < 2048; idx += 256) {       // contract p
        int t = idx >> 6, i = (idx >> 3) & 7, q = idx & 7;
        float acc = 0.f;
        #pragma unroll
        for (int p = 0; p < 8; ++p) acc += Cs[p][i] * bufB[t * 64 + p * 8 + q];
        bufA[idx] = acc;
    }
    __syncthreads();
    const int so_s = blockIdx.x >> 6;                   // W is [s][o][...]
    const int so_o = blockIdx.x & 63;
    for (int idx = tid; idx < 2048; idx += 256) {       // contract q + 1/8
        int t = idx >> 6, i = (idx >> 3) & 7, j = idx & 7;
        float acc = 0.f;
        #pragma unroll
        for (int q = 0; q < 8; ++q) acc += Cs[q][j] * bufA[t * 64 + i * 8 + q];
        VeffT[((size_t)so_s * KDIM + idx) * NF + so_o] = 0.125f * acc;
    }
}

// ---------------------------------------------------------------------------
// Kernel 2: xsumT[s][k][b] = sum_c x[b, s*256 + c*32 + (k>>6), (k&63)]
// Pure HBM stream: 134 MB in, 16 MB out.  Block = (btile of 32 b, s, kchunk
// of 256 k = 4 t-rows).  float4 loads (1 KiB/wave-instr), c-sum in regs,
// LDS transpose [256][33], coalesced transposed store.
// 33.8 KiB LDS -> 4 blocks/CU -> 16 waves/CU of MLP.
// ---------------------------------------------------------------------------
__global__ __launch_bounds__(256) void csumT_kernel(const float* __restrict__ x,
                                                    float* __restrict__ xsumT,
                                                    int B) {
    __shared__ float Xt[256 * 33];          // [k_local][b_local], pad 33
    const int bt  = blockIdx.x;             // b-tile (32 batches)
    const int kc  = blockIdx.y;             // k-chunk: t in [kc*4, kc*4+4)
    const int s   = blockIdx.z;
    const int tid = threadIdx.x;
    const int lane = tid & 63;
    const int w    = tid >> 6;              // wave 0..3

    const float4* x4 = (const float4*)x;
    #pragma unroll
    for (int bi = 0; bi < 8; ++bi) {
        const int b_local = w * 8 + bi;
        // float4 index: (b*512 + s*256 + c*32 + kc*4)*16 + lane
        //   lane>>4 selects t-offset row, lane&15 the ij-float4 -> 4*lane = k_local
        size_t base = ((size_t)(bt * 32 + b_local) * 512 + s * 256 + kc * 4) * 16 + lane;
        float4 a = make_float4(0.f, 0.f, 0.f, 0.f);
        #pragma unroll
        for (int c = 0; c < 8; ++c) {
            float4 v = x4[base + (size_t)c * 512];      // c stride = 32 tp * 16 f4
            a.x += v.x; a.y += v.y; a.z += v.z; a.w += v.w;
        }
        float* p = &Xt[lane * 132 + b_local];           // k_local = 4*lane (+0..3)
        p[0] = a.x; p[33] = a.y; p[66] = a.z; p[99] = a.w;
    }
    __syncthreads();

    // write out: k = pass*8 + (tid>>5), b = tid&31; 128 B segments per half-wave
    const int b  = tid & 31;
    const int kk = tid >> 5;
    float* dst = xsumT + ((size_t)s * KDIM + kc * 256) * B + bt * 32 + b;
    #pragma unroll
    for (int pass = 0; pass < 32; ++pass) {
        int k = pass * 8 + kk;
        dst[(size_t)k * B] = Xt[k * 33 + b];
    }
}

// ---------------------------------------------------------------------------
// Kernel 3: partial GEMM.  lanes -> batch, so x-operand loads are coalesced
// and the weight row VeffT[s][k][og*16..] is wave-uniform (scalar/broadcast).
// Inner loop: 1 coalesced load + 16 reg FMAs, zero LDS, zero barriers.
// Grid (B/64, 16 k-splits, 2 s) = 512 blocks; wave og owns 16 outputs.
// part[ky][s][o][b] partials reduced by kernel 4.
// ---------------------------------------------------------------------------
__global__ __launch_bounds__(256) void gemm_kernel(const float* __restrict__ xsumT,
                                                   const float* __restrict__ VeffT,
                                                   float* __restrict__ part,
                                                   int B) {
    const int bt   = blockIdx.x;
    const int ky   = blockIdx.y;            // k-split: k in [ky*128, ky*128+128)
    const int s    = blockIdx.z;
    const int lane = threadIdx.x & 63;
    const int og   = __builtin_amdgcn_readfirstlane(threadIdx.x >> 6);

    const float* xp = xsumT + ((size_t)s * KDIM + ky * 128) * B + bt * 64 + lane;
    const float* wp = VeffT + ((size_t)s * KDIM + ky * 128) * NF + og * 16;

    float acc[16];
    #pragma unroll
    for (int i = 0; i < 16; ++i) acc[i] = 0.f;

    #pragma unroll 4
    for (int k = 0; k < 128; ++k) {
        float xv = xp[(size_t)k * B];
        const float4* w4 = (const float4*)(wp + (size_t)k * NF);
        float4 w0 = w4[0], w1 = w4[1], w2 = w4[2], w3 = w4[3];
        acc[0]  += w0.x * xv; acc[1]  += w0.y * xv; acc[2]  += w0.z * xv; acc[3]  += w0.w * xv;
        acc[4]  += w1.x * xv; acc[5]  += w1.y * xv; acc[6]  += w1.z * xv; acc[7]  += w1.w * xv;
        acc[8]  += w2.x * xv; acc[9]  += w2.y * xv; acc[10] += w2.z * xv; acc[11] += w2.w * xv;
        acc[12] += w3.x * xv; acc[13] += w3.y * xv; acc[14] += w3.z * xv; acc[15] += w3.w * xv;
    }

    float* pp = part + ((size_t)ky * 128 + s * 64 + og * 16) * B + bt * 64 + lane;
    #pragma unroll
    for (int o = 0; o < 16; ++o) pp[(size_t)o * B] = acc[o];
}

// ---------------------------------------------------------------------------
// Kernel 4: reduce 16 k-split partials + bias + LeakyReLU.  part is
// L2/L3-resident (8.4 MB just written).  Coalesced reads along b.
// ---------------------------------------------------------------------------
__global__ __launch_bounds__(256) void epi_kernel(const float* __restrict__ part,
                                                  const float* __restrict__ bias,
                                                  float* __restrict__ out,
                                                  int B) {
    const int g  = blockIdx.x * 256 + threadIdx.x;
    const int b  = g & (B - 1);             // B is a power of two (1024)
    const int so = g / B;                   // s*64 + o  (0..127)
    float sum = bias[so];
    #pragma unroll
    for (int ky = 0; ky < 16; ++ky)
        sum += part[((size_t)ky * 128 + so) * B + b];
    sum = (sum >= 0.f) ? sum : SLOPE * sum;
    out[(size_t)b * 128 + so] = sum;
}

extern "C" void kernel_launch(void* const* d_in, const int* in_sizes, int n_in,
                              void* d_out, int out_size, void* d_ws, size_t ws_size,
                              hipStream_t stream) {
    const float* x    = (const float*)d_in[0];   // [B,1,512,8,8]
    const float* W    = (const float*)d_in[1];   // [2,64,32,8,8]
    const float* bias = (const float*)d_in[2];   // [2,64]
    float* out = (float*)d_out;                  // [B,128]

    const int B = in_sizes[0] / (512 * 64);      // 1024

    // workspace layout (floats): VeffT 0.5M | xsumT 2*2048*B | part 16*128*B
    float* VeffT = (float*)d_ws;                             // 2*2048*64  = 1 MiB
    float* xsumT = VeffT + (size_t)NSW * KDIM * NF;          // 2*2048*B   = 16 MiB
    float* part  = xsumT + (size_t)NSW * KDIM * B;           // 16*128*B   = 8 MiB

    veff_kernel<<<NSW * NF, 256, 0, stream>>>(W, VeffT);
    csumT_kernel<<<dim3(B / 32, 8, NSW), 256, 0, stream>>>(x, xsumT, B);
    gemm_kernel<<<dim3(B / 64, 16, NSW), 256, 0, stream>>>(xsumT, VeffT, part, B);
    epi_kernel<<<(B * 128) / 256, 256, 0, stream>>>(part, bias, out, B);
}

// Round 3
// 213.033 us; speedup vs baseline: 1.0669x; 1.0669x over previous
//
#include <hip/hip_runtime.h>

#define NSW 2
#define NDCT 32
#define NF 64
#define KDIM 2048          // 32 t * 64 spatial
#define SLOPE 0.02f
#define PI_F 3.14159265358979323846f

// ---------------------------------------------------------------------------
// Kernel 1: Veff4[s][k4][o] (float4 over c=k&3) =
//   0.125 * sum_{f,p,q} Ct[f,t] Cs[p,i] Cs[q,j] W[s,o,f,p,q],  k = t*64+i*8+j.
// float4-grouped-by-k layout so the fused GEMM loads 16 B/lane coalesced.
// 128 blocks, ~4 us.
// ---------------------------------------------------------------------------
__global__ __launch_bounds__(256) void veff_kernel(const float* __restrict__ W,
                                                   float* __restrict__ Veff) {
    __shared__ float Ct[32][32];   // [f][t] = 2*cos(pi*(2t+1)*f/64)
    __shared__ float Cs[8][8];     // [p][i] = 2*cos(pi*(2i+1)*p/16)
    __shared__ float bufA[2048];
    __shared__ float bufB[2048];
    const int tid = threadIdx.x;

    for (int idx = tid; idx < 1024; idx += 256) {
        int f = idx >> 5, t = idx & 31;
        Ct[f][t] = 2.0f * cosf(PI_F * (float)((2 * t + 1) * f) * (1.0f / 64.0f));
    }
    if (tid < 64) {
        int p = tid >> 3, i = tid & 7;
        Cs[p][i] = 2.0f * cosf(PI_F * (float)((2 * i + 1) * p) * (1.0f / 16.0f));
    }
    const float* Wso = W + blockIdx.x * 2048;   // [f(32)][p(8)][q(8)]
    for (int idx = tid; idx < 2048; idx += 256) bufA[idx] = Wso[idx];
    __syncthreads();

    for (int idx = tid; idx < 2048; idx += 256) {       // contract f
        int t = idx >> 6, pq = idx & 63;
        float acc = 0.f;
        #pragma unroll
        for (int f = 0; f < 32; ++f) acc += Ct[f][t] * bufA[f * 64 + pq];
        bufB[idx] = acc;
    }
    __syncthreads();
    for (int idx = tid; idx < 2048; idx += 256) {       // contract p
        int t = idx >> 6, i = (idx >> 3) & 7, q = idx & 7;
        float acc = 0.f;
        #pragma unroll
        for (int p = 0; p < 8; ++p) acc += Cs[p][i] * bufB[t * 64 + p * 8 + q];
        bufA[idx] = acc;
    }
    __syncthreads();
    const int so_s = blockIdx.x >> 6;                   // W is [s][o][...]
    const int so_o = blockIdx.x & 63;
    for (int idx = tid; idx < 2048; idx += 256) {       // contract q + 1/8
        int t = idx >> 6, i = (idx >> 3) & 7, j = idx & 7;
        float acc = 0.f;
        #pragma unroll
        for (int q = 0; q < 8; ++q) acc += Cs[q][j] * bufA[t * 64 + i * 8 + q];
        // layout: [s][k4 = idx>>2][o][c = idx&3]
        Veff[(((size_t)so_s * 512 + (idx >> 2)) * 64 + so_o) * 4 + (idx & 3)] =
            0.125f * acc;
    }
}

// ---------------------------------------------------------------------------
// Kernel 2 (fused v2): per block = (4 batches, one subwindow s).
//   Phase 1: stream x[b, s*256.., :] (256 KiB) from HBM, c-sum into LDS Xs4.
//   Phase 2: thread (o = tid&63, kq = tid>>6) iterates its k-quarter:
//     1 coalesced float4 weight load STRAIGHT FROM L2 (Veff is 1 MiB,
//     L2-resident; no LDS staging, no inner-loop barriers) +
//     4 uniform-address LDS broadcasts + 16 FMAs.
// ONE barrier total (vs 33 in round 0).  LDS 36 KiB.
// ---------------------------------------------------------------------------
__global__ __launch_bounds__(256) void fused2_kernel(const float* __restrict__ x,
                                                     const float* __restrict__ Veff,
                                                     const float* __restrict__ bias,
                                                     float* __restrict__ out) {
    __shared__ float4 Xs4[4 * 512];     // [b][k4], k4 = t*16+ij4  (32 KiB)
    __shared__ float  part[4][4][64];   // [kq][b][o]              (4 KiB)
    const int s   = blockIdx.y;
    const int b0  = blockIdx.x * 4;
    const int tid = threadIdx.x;

    // ---- Phase 1: xsum[b, t, ij] = sum_c x[b, s*256 + c*32 + t, ij] ----
    const float4* xbase = (const float4*)x;
    #pragma unroll
    for (int b = 0; b < 4; ++b) {
        #pragma unroll
        for (int r = 0; r < 2; ++r) {
            int k4 = tid + r * 256;                       // 0..511
            const float4* xp = xbase + (((size_t)(b0 + b) * 512 + s * 256) * 16 + k4);
            float4 acc = make_float4(0.f, 0.f, 0.f, 0.f);
            #pragma unroll
            for (int c = 0; c < 8; ++c) {
                float4 v = xp[c * 512];                   // c stride = 32 tp * 16 f4
                acc.x += v.x; acc.y += v.y; acc.z += v.z; acc.w += v.w;
            }
            Xs4[b * 512 + k4] = acc;
        }
    }
    __syncthreads();

    // ---- Phase 2: feat[b,o] = dot(xsum[b,:], Veff[s,:,o]) ----
    const int o  = tid & 63;
    const int kq = tid >> 6;
    const float4* wp = (const float4*)Veff + ((size_t)s * 512 + kq * 128) * 64 + o;
    const float4* xq = Xs4 + kq * 128;

    float acc0 = 0.f, acc1 = 0.f, acc2 = 0.f, acc3 = 0.f;
    #pragma unroll 4
    for (int m = 0; m < 128; ++m) {
        float4 w  = wp[(size_t)m * 64];                   // 16 B/lane, L2-coalesced
        float4 x0 = xq[0 * 512 + m];                      // uniform addr: broadcast
        float4 x1 = xq[1 * 512 + m];
        float4 x2 = xq[2 * 512 + m];
        float4 x3 = xq[3 * 512 + m];
        acc0 += w.x * x0.x + w.y * x0.y + w.z * x0.z + w.w * x0.w;
        acc1 += w.x * x1.x + w.y * x1.y + w.z * x1.z + w.w * x1.w;
        acc2 += w.x * x2.x + w.y * x2.y + w.z * x2.z + w.w * x2.w;
        acc3 += w.x * x3.x + w.y * x3.y + w.z * x3.z + w.w * x3.w;
    }

    part[kq][0][o] = acc0;
    part[kq][1][o] = acc1;
    part[kq][2][o] = acc2;
    part[kq][3][o] = acc3;
    __syncthreads();
    {
        int b = tid >> 6, oo = tid & 63;
        float f = part[0][b][oo] + part[1][b][oo] + part[2][b][oo] + part[3][b][oo]
                + bias[s * 64 + oo];
        f = (f >= 0.f) ? f : SLOPE * f;
        out[(size_t)(b0 + b) * 128 + s * 64 + oo] = f;
    }
}

extern "C" void kernel_launch(void* const* d_in, const int* in_sizes, int n_in,
                              void* d_out, int out_size, void* d_ws, size_t ws_size,
                              hipStream_t stream) {
    const float* x    = (const float*)d_in[0];   // [B,1,512,8,8]
    const float* W    = (const float*)d_in[1];   // [2,64,32,8,8]
    const float* bias = (const float*)d_in[2];   // [2,64]
    float* out = (float*)d_out;                  // [B,128]

    const int B = in_sizes[0] / (512 * 64);      // 1024

    float* Veff = (float*)d_ws;                  // 2*512*64 float4 = 1 MiB

    veff_kernel<<<NSW * NF, 256, 0, stream>>>(W, Veff);
    fused2_kernel<<<dim3(B / 4, NSW), 256, 0, stream>>>(x, Veff, bias, out);
}